// Round 9
// baseline (130.948 us; speedup 1.0000x reference)
//
#include <hip/hip_runtime.h>
#include <math.h>

// Problem constants (B=2, C=64, CI=32, T=16, H=W=14)
#define S3   3136      // per-channel spatial size = 16*196
#define PB   100352    // per-batch proj elements = 32*3136
#define XB   200704    // per-batch x elements = 64*3136
#define NN   6272      // CI*H*W = spatial attention sequence length
#define TGC  49        // (historical) temporal gram chunks

typedef __attribute__((ext_vector_type(8))) short bf16x8;   // 8 bf16 = 4 VGPRs
typedef __attribute__((ext_vector_type(16))) float f32x16;  // MFMA C/D 32x32
typedef __attribute__((ext_vector_type(4))) uint u32x4;

__device__ inline ushort f2bf(float f) {     // RNE f32 -> bf16
    uint u = __float_as_uint(f);
    return (ushort)((u + 0x7FFFu + ((u >> 16) & 1u)) >> 16);
}

__device__ inline uint cvtpk(float lo, float hi) {   // pack 2 f32 -> 2 bf16
    uint r;
    asm("v_cvt_pk_bf16_f32 %0, %1, %2" : "=v"(r) : "v"(lo), "v"(hi));
    return r;
}

__device__ inline void swap32(uint &a, uint &b) {    // a=[a_lo|b_lo], b=[a_hi|b_hi]
    asm("v_permlane32_swap_b32 %0, %1" : "+v"(a), "+v"(b));
}

// ---------------------------------------------------------------------------
// Kernel 1: all 6 QKV projections, 8x o-split (4 outputs per thread) for
// latency-hiding TLP: grid (25,6,8) = 2400 blocks. (verbatim round-6)
// ---------------------------------------------------------------------------
__global__ __launch_bounds__(256) void proj_kernel(
    const float* __restrict__ x,
    const float* __restrict__ W0, const float* __restrict__ b0,
    const float* __restrict__ W1, const float* __restrict__ b1,
    const float* __restrict__ W2, const float* __restrict__ b2,
    const float* __restrict__ W3, const float* __restrict__ b3,
    const float* __restrict__ W4, const float* __restrict__ b4,
    const float* __restrict__ W5, const float* __restrict__ b5,
    ushort* __restrict__ Qb, ushort* __restrict__ Kb, ushort* __restrict__ Vb,
    float* __restrict__ Qt, float* __restrict__ Kt, float* __restrict__ Vt)
{
    const float* Wp; const float* bp;
    switch (blockIdx.y) {
        case 0:  Wp = W0; bp = b0; break;
        case 1:  Wp = W1; bp = b1; break;
        case 2:  Wp = W2; bp = b2; break;
        case 3:  Wp = W3; bp = b3; break;
        case 4:  Wp = W4; bp = b4; break;
        default: Wp = W5; bp = b5; break;
    }
    int z = blockIdx.z;               // o in [z*4, z*4+4)

    int gid = blockIdx.x * 256 + threadIdx.x;
    if (gid >= 2 * S3) return;
    int b = (gid >= S3) ? 1 : 0;
    int s = gid - b * S3;

    float xr[64];
    #pragma unroll
    for (int c = 0; c < 64; ++c) xr[c] = x[(size_t)b * XB + (size_t)c * S3 + s];

    float a[4];
    #pragma unroll
    for (int oo = 0; oo < 4; ++oo) {
        int o = z * 4 + oo;
        float acc = bp[o];
        #pragma unroll
        for (int c = 0; c < 64; ++c) acc = fmaf(Wp[o * 64 + c], xr[c], acc);
        a[oo] = acc;
    }

    if (blockIdx.y < 2) {
        // bf16 transposed [n][16]: o = z*4 + 2k + h -> t = z*2+k, n = h*S3+s
        const float sc = (blockIdx.y == 0) ? 0.36067376022224085f : 1.0f; // 0.25*log2e
        ushort* ob = (blockIdx.y == 0) ? Qb : Kb;
        #pragma unroll
        for (int h = 0; h < 2; ++h) {
            int n = h * S3 + s;
            uint u0 = f2bf(a[0 + h] * sc) | ((uint)f2bf(a[2 + h] * sc) << 16);
            *(uint*)(ob + ((size_t)(b * NN + n) * 16 + z * 2)) = u0;
        }
    } else if (blockIdx.y == 2) {
        // bf16 natural [t][n]: o -> t = o>>1, n = (o&1)*S3+s
        #pragma unroll
        for (int oo = 0; oo < 4; ++oo) {
            int o = z * 4 + oo;
            Vb[(size_t)(b * 16 + (o >> 1)) * NN + (o & 1) * S3 + s] = f2bf(a[oo]);
        }
    } else {
        float* op = (blockIdx.y == 3) ? Qt : (blockIdx.y == 4) ? Kt : Vt;
        #pragma unroll
        for (int oo = 0; oo < 4; ++oo)
            op[(size_t)b * PB + (size_t)(z * 4 + oo) * S3 + s] = a[oo];
    }
}

// ---------------------------------------------------------------------------
// Kernel 2: spatial flash attn + temporal gram/softmax + yt + out-proj +
// residual, fully fused. Grid (196, 2) x 512 threads (8 waves).
// __launch_bounds__(512,4) forces VGPR<=128 -> 2 blocks/CU -> all 392 blocks
// co-resident (deadlock-free by arithmetic).
//  Stage G: each block computes a 32-n-row Gram partial of its 1/196 slice,
//           atomicAdd into Gp[b][256]; release-bump cnt[b] (target 196).
//  m-loop: verbatim verified 32x32x16 flash attention (round-3/6/8).
//  Post-loop: wait cnt (already satisfied in practice, single acquire),
//           temporal softmax from Gp, then ys+yt merge and out-projection.
// ---------------------------------------------------------------------------
__global__ __launch_bounds__(512, 4) void attn_merge_kernel(
    const ushort* __restrict__ Qb, const ushort* __restrict__ Kb,
    const ushort* __restrict__ Vb, const float* __restrict__ Qt,
    const float* __restrict__ Kt, float* __restrict__ Gp,
    uint* __restrict__ cnt, const float* __restrict__ Vt,
    const float* __restrict__ x, const float* __restrict__ Ww,
    const float* __restrict__ bw, float* __restrict__ out)
{
    __shared__ float shpool[4352];       // union: gram staging (1024) / Yred 8x17x32
    __shared__ float Ash[16][17];
    __shared__ float Ysh[32][17];        // [ci][s]
#define YR(w, t, c) shpool[(((w) * 17) + (t)) * 32 + (c)]

    int b   = blockIdx.y;
    int s0  = blockIdx.x * 16;
    int tid = threadIdx.x;

    // --- stage G: gram partial over n-rows [bx*32, bx*32+32) ---
    {
        float* qs = shpool;              // 512 floats
        float* ks = shpool + 512;        // 512 floats
        size_t gbase = (size_t)b * PB + (size_t)blockIdx.x * 512;
        if (tid < 128)
            ((float4*)qs)[tid] = ((const float4*)(Qt + gbase))[tid];
        else if (tid < 256)
            ((float4*)ks)[tid - 128] = ((const float4*)(Kt + gbase))[tid - 128];
        __syncthreads();
        if (tid < 256) {
            int t = tid >> 4, s = tid & 15;
            float acc = 0.0f;
            #pragma unroll 8
            for (int n = 0; n < 32; ++n)
                acc = fmaf(qs[n * 16 + t], ks[n * 16 + s], acc);
            atomicAdd(&Gp[b * 256 + tid], acc);
        }
        __syncthreads();                 // drains atomics (vmcnt 0 before barrier)
        if (tid == 0)
            __hip_atomic_fetch_add(&cnt[b], 1u, __ATOMIC_RELEASE,
                                   __HIP_MEMORY_SCOPE_AGENT);
    }

    // --- spatial flash attention, 32x32x16, m round-robin over 8 waves ---
    int wave = __builtin_amdgcn_readfirstlane(tid >> 6);
    int lane = tid & 63;
    int col  = lane & 31;                  // n-col / m-row / t'-row lane index
    int h    = lane >> 5;                  // half: k = h*8+e
    int nq   = (col >> 4) * S3 + s0 + (col & 15);   // this lane's n column

    bf16x8 qf = *(const bf16x8*)(Qb + ((size_t)(b * NN + nq) * 16 + h * 8));

    const bf16x8 vzero = {0, 0, 0, 0, 0, 0, 0, 0};
    const bf16x8 vones = {16256, 16256, 16256, 16256, 16256, 16256, 16256, 16256};
    f32x16 yacc;
    #pragma unroll
    for (int r = 0; r < 16; ++r) yacc[r] = 0.0f;
    f32x16 zero16 = yacc;

    for (int i = wave; i < 196; i += 8) {
        int mb = i * 32;
        // K fragment (A-operand): A[row=m=mb+col][k=t=h*8+e]
        bf16x8 kf = *(const bf16x8*)(Kb + ((size_t)(b * NN + mb + col) * 16 + h * 8));
        // V fragments (A-operand) for the two PV k-steps: A[row=t'=col][k=m]
        bf16x8 vf0 = vzero, vf1 = vzero;
        if (col < 16) {
            const ushort* vp = Vb + ((size_t)(b * 16 + col) * NN + mb + h * 8);
            vf0 = *(const bf16x8*)(vp);
            vf1 = *(const bf16x8*)(vp + 16);
        } else if (col == 16) { vf0 = vones; vf1 = vones; }   // l-row

        // S^T tile: D[m-row][n-col], rows (r&3)+8*(r>>2)+4h, col = n
        f32x16 st = __builtin_amdgcn_mfma_f32_32x32x16_bf16(kf, qf, zero16, 0, 0, 0);
        float pv[16];
        #pragma unroll
        for (int r = 0; r < 16; ++r) pv[r] = __builtin_amdgcn_exp2f(st[r]);

        // pack to bf16 pairs; permlane32_swap routes rows to B-operand k-slots
        uint X0 = cvtpk(pv[0],  pv[1]),  X1 = cvtpk(pv[2],  pv[3]);
        uint Y0 = cvtpk(pv[4],  pv[5]),  Y1 = cvtpk(pv[6],  pv[7]);
        uint X2 = cvtpk(pv[8],  pv[9]),  X3 = cvtpk(pv[10], pv[11]);
        uint Y2 = cvtpk(pv[12], pv[13]), Y3 = cvtpk(pv[14], pv[15]);
        swap32(X0, Y0); swap32(X1, Y1);
        swap32(X2, Y2); swap32(X3, Y3);
        u32x4 pb0 = {X0, X1, Y0, Y1};    // B-frag rows mb+0..15
        u32x4 pb1 = {X2, X3, Y2, Y3};    // B-frag rows mb+16..31

        yacc = __builtin_amdgcn_mfma_f32_32x32x16_bf16(
                   vf0, __builtin_bit_cast(bf16x8, pb0), yacc, 0, 0, 0);
        yacc = __builtin_amdgcn_mfma_f32_32x32x16_bf16(
                   vf1, __builtin_bit_cast(bf16x8, pb1), yacc, 0, 0, 0);
    }

    // per-wave partials to LDS: rows 0..15 = y[t], row 16 = l (h==0 reg 8)
    #pragma unroll
    for (int r = 0; r < 8; ++r) {
        int t = (r & 3) + 8 * (r >> 2) + 4 * h;
        YR(wave, t, col) = yacc[r];
    }
    if (h == 0) YR(wave, 16, col) = yacc[8];
    __syncthreads();

    // --- wait for all 196 gram partials of this b (satisfied in practice) ---
    if (tid == 0) {
        long polls = 0;
        while (__hip_atomic_load(&cnt[b], __ATOMIC_RELAXED,
                                 __HIP_MEMORY_SCOPE_AGENT) < 196u) {
            __builtin_amdgcn_s_sleep(2);
            if (++polls > 10000000L) break;   // fail to wrong answer, not hang
        }
        (void)__hip_atomic_load(&cnt[b], __ATOMIC_ACQUIRE,
                                __HIP_MEMORY_SCOPE_AGENT);
    }
    __syncthreads();

    // --- temporal softmax: logits L[t][s] = 0.25 * Gp[b][t*16+s] ---
    if (tid < 16) {
        int t = tid;
        const float* Lr = &Gp[b * 256 + t * 16];
        float mx = -1e30f;
        #pragma unroll
        for (int s = 0; s < 16; ++s) mx = fmaxf(mx, Lr[s] * 0.25f);
        float e[16]; float sm = 0.0f;
        #pragma unroll
        for (int s = 0; s < 16; ++s) { e[s] = __expf(Lr[s] * 0.25f - mx); sm += e[s]; }
        float inv = 1.0f / sm;
        #pragma unroll
        for (int s = 0; s < 16; ++s) Ash[s][t] = e[s] * inv;
    }
    __syncthreads();

    // --- epilogue 1: one (t, col) per thread -> Ysh[ci][s] = ys + yt ---
    {
        int t    = tid >> 5;               // 0..15
        int c2   = tid & 31;
        float ysum = 0.0f, lsum = 0.0f;
        #pragma unroll
        for (int w = 0; w < 8; ++w) {
            ysum += YR(w, t, c2);
            lsum += YR(w, 16, c2);
        }
        float ys = ysum / lsum;

        int t2   = c2 & 15;                // s within chunk
        int half = c2 >> 4;
        const float4* vp = (const float4*)(Vt + (size_t)b * PB + (size_t)t * NN
                                           + (size_t)half * S3 + s0);
        float4 v0 = vp[0], v1 = vp[1], v2 = vp[2], v3 = vp[3];
        float yt = Ash[0][t2] * v0.x;
        yt = fmaf(Ash[1][t2],  v0.y, yt); yt = fmaf(Ash[2][t2],  v0.z, yt);
        yt = fmaf(Ash[3][t2],  v0.w, yt); yt = fmaf(Ash[4][t2],  v1.x, yt);
        yt = fmaf(Ash[5][t2],  v1.y, yt); yt = fmaf(Ash[6][t2],  v1.z, yt);
        yt = fmaf(Ash[7][t2],  v1.w, yt); yt = fmaf(Ash[8][t2],  v2.x, yt);
        yt = fmaf(Ash[9][t2],  v2.y, yt); yt = fmaf(Ash[10][t2], v2.z, yt);
        yt = fmaf(Ash[11][t2], v2.w, yt); yt = fmaf(Ash[12][t2], v3.x, yt);
        yt = fmaf(Ash[13][t2], v3.y, yt); yt = fmaf(Ash[14][t2], v3.z, yt);
        yt = fmaf(Ash[15][t2], v3.w, yt);

        Ysh[2 * t + half][t2] = ys + yt;   // [ci][s]
    }
    __syncthreads();

    // --- epilogue 2: output projection + residual, 64c x 16s, 2 per thread ---
    {
        int s  = tid & 15;
        int cg = tid >> 4;                 // 0..31
        #pragma unroll
        for (int kk = 0; kk < 2; ++kk) {
            int c = cg + kk * 32;
            float acc = bw[c];
            const float4* wr = (const float4*)(Ww + c * 32);
            #pragma unroll
            for (int cb = 0; cb < 8; ++cb) {
                float4 w4 = wr[cb];
                acc = fmaf(w4.x, Ysh[cb * 4 + 0][s], acc);
                acc = fmaf(w4.y, Ysh[cb * 4 + 1][s], acc);
                acc = fmaf(w4.z, Ysh[cb * 4 + 2][s], acc);
                acc = fmaf(w4.w, Ysh[cb * 4 + 3][s], acc);
            }
            size_t o = (size_t)b * XB + (size_t)c * S3 + s0 + s;
            out[o] = x[o] + acc;
        }
    }
#undef YR
}

// ---------------------------------------------------------------------------
extern "C" void kernel_launch(void* const* d_in, const int* in_sizes, int n_in,
                              void* d_out, int out_size, void* d_ws, size_t ws_size,
                              hipStream_t stream)
{
    const float* x   = (const float*)d_in[0];
    const float* Wqs = (const float*)d_in[1];  const float* bqs = (const float*)d_in[2];
    const float* Wks = (const float*)d_in[3];  const float* bks = (const float*)d_in[4];
    const float* Wvs = (const float*)d_in[5];  const float* bvs = (const float*)d_in[6];
    const float* Wqt = (const float*)d_in[7];  const float* bqt = (const float*)d_in[8];
    const float* Wkt = (const float*)d_in[9];  const float* bkt = (const float*)d_in[10];
    const float* Wvt = (const float*)d_in[11]; const float* bvt = (const float*)d_in[12];
    const float* Ww  = (const float*)d_in[13]; const float* bw  = (const float*)d_in[14];

    // workspace layout (float units); ~0.91M floats = 3.6 MB
    float* ws = (float*)d_ws;
    ushort* Qb = (ushort*)(ws);            // 200704 bf16
    ushort* Kb = (ushort*)(ws + 100352);
    ushort* Vb = (ushort*)(ws + 200704);
    float* Qt  = ws + 301056;              // 200704
    float* Kt  = ws + 501760;
    float* Vt  = ws + 702464;
    float* Gp  = ws + 903168;              // 2*256 floats (atomic gram accum)
    uint*  cnt = (uint*)(ws + 903680);     // 2 counters

    hipMemsetAsync(Gp, 0, 512 * sizeof(float) + 2 * sizeof(uint), stream);

    proj_kernel<<<dim3(25, 6, 8), 256, 0, stream>>>(
        x, Wqs, bqs, Wks, bks, Wvs, bvs, Wqt, bqt, Wkt, bkt, Wvt, bvt,
        Qb, Kb, Vb, Qt, Kt, Vt);

    attn_merge_kernel<<<dim3(196, 2), 512, 0, stream>>>(
        Qb, Kb, Vb, Qt, Kt, Gp, cnt, Vt, x, Ww, bw, (float*)d_out);
}

// Round 10
// 124.906 us; speedup vs baseline: 1.0484x; 1.0484x over previous
//
#include <hip/hip_runtime.h>
#include <math.h>

// Problem constants (B=2, C=64, CI=32, T=16, H=W=14)
#define S3   3136      // per-channel spatial size = 16*196
#define PB   100352    // per-batch proj elements = 32*3136
#define XB   200704    // per-batch x elements = 64*3136
#define NN   6272      // CI*H*W = spatial attention sequence length
#define TGC  49        // temporal gram chunks (128 n each)

typedef __attribute__((ext_vector_type(8))) short bf16x8;   // 8 bf16 = 4 VGPRs
typedef __attribute__((ext_vector_type(16))) float f32x16;  // MFMA C/D 32x32
typedef __attribute__((ext_vector_type(4))) uint u32x4;

__device__ inline ushort f2bf(float f) {     // RNE f32 -> bf16
    uint u = __float_as_uint(f);
    return (ushort)((u + 0x7FFFu + ((u >> 16) & 1u)) >> 16);
}

__device__ inline uint cvtpk(float lo, float hi) {   // pack 2 f32 -> 2 bf16
    uint r;
    asm("v_cvt_pk_bf16_f32 %0, %1, %2" : "=v"(r) : "v"(lo), "v"(hi));
    return r;
}

__device__ inline void swap32(uint &a, uint &b) {    // a=[a_lo|b_lo], b=[a_hi|b_hi]
    asm("v_permlane32_swap_b32 %0, %1" : "+v"(a), "+v"(b));
}

// ---------------------------------------------------------------------------
// Kernel 1: all 6 QKV projections, 8x o-split (4 outputs per thread) for
// latency-hiding TLP: grid (25,6,8) = 2400 blocks. (verbatim round-6)
// ---------------------------------------------------------------------------
__global__ __launch_bounds__(256) void proj_kernel(
    const float* __restrict__ x,
    const float* __restrict__ W0, const float* __restrict__ b0,
    const float* __restrict__ W1, const float* __restrict__ b1,
    const float* __restrict__ W2, const float* __restrict__ b2,
    const float* __restrict__ W3, const float* __restrict__ b3,
    const float* __restrict__ W4, const float* __restrict__ b4,
    const float* __restrict__ W5, const float* __restrict__ b5,
    ushort* __restrict__ Qb, ushort* __restrict__ Kb, ushort* __restrict__ Vb,
    float* __restrict__ Qt, float* __restrict__ Kt, float* __restrict__ Vt)
{
    const float* Wp; const float* bp;
    switch (blockIdx.y) {
        case 0:  Wp = W0; bp = b0; break;
        case 1:  Wp = W1; bp = b1; break;
        case 2:  Wp = W2; bp = b2; break;
        case 3:  Wp = W3; bp = b3; break;
        case 4:  Wp = W4; bp = b4; break;
        default: Wp = W5; bp = b5; break;
    }
    int z = blockIdx.z;               // o in [z*4, z*4+4)

    int gid = blockIdx.x * 256 + threadIdx.x;
    if (gid >= 2 * S3) return;
    int b = (gid >= S3) ? 1 : 0;
    int s = gid - b * S3;

    float xr[64];
    #pragma unroll
    for (int c = 0; c < 64; ++c) xr[c] = x[(size_t)b * XB + (size_t)c * S3 + s];

    float a[4];
    #pragma unroll
    for (int oo = 0; oo < 4; ++oo) {
        int o = z * 4 + oo;
        float acc = bp[o];
        #pragma unroll
        for (int c = 0; c < 64; ++c) acc = fmaf(Wp[o * 64 + c], xr[c], acc);
        a[oo] = acc;
    }

    if (blockIdx.y < 2) {
        // bf16 transposed [n][16]: o = z*4 + 2k + h -> t = z*2+k, n = h*S3+s
        const float sc = (blockIdx.y == 0) ? 0.36067376022224085f : 1.0f; // 0.25*log2e
        ushort* ob = (blockIdx.y == 0) ? Qb : Kb;
        #pragma unroll
        for (int h = 0; h < 2; ++h) {
            int n = h * S3 + s;
            uint u0 = f2bf(a[0 + h] * sc) | ((uint)f2bf(a[2 + h] * sc) << 16);
            *(uint*)(ob + ((size_t)(b * NN + n) * 16 + z * 2)) = u0;
        }
    } else if (blockIdx.y == 2) {
        // bf16 natural [t][n]: o -> t = o>>1, n = (o&1)*S3+s
        #pragma unroll
        for (int oo = 0; oo < 4; ++oo) {
            int o = z * 4 + oo;
            Vb[(size_t)(b * 16 + (o >> 1)) * NN + (o & 1) * S3 + s] = f2bf(a[oo]);
        }
    } else {
        float* op = (blockIdx.y == 3) ? Qt : (blockIdx.y == 4) ? Kt : Vt;
        #pragma unroll
        for (int oo = 0; oo < 4; ++oo)
            op[(size_t)b * PB + (size_t)(z * 4 + oo) * S3 + s] = a[oo];
    }
}

// ---------------------------------------------------------------------------
// Kernel 2: temporal Gram partials, grid (49, 2). (verbatim round-6 branch)
// ---------------------------------------------------------------------------
__global__ __launch_bounds__(256) void gram_kernel(
    const float* __restrict__ Qt, const float* __restrict__ Kt,
    float* __restrict__ Gp)
{
    __shared__ float qs[128 * 16], ks[128 * 16];
    int b = blockIdx.y;
    int c = blockIdx.x;                  // 0..48
    size_t base = (size_t)b * PB + (size_t)c * 2048;
    for (int i = threadIdx.x; i < 512; i += 256) {
        ((float4*)qs)[i] = ((const float4*)(Qt + base))[i];
        ((float4*)ks)[i] = ((const float4*)(Kt + base))[i];
    }
    __syncthreads();
    int t = threadIdx.x >> 4, s = threadIdx.x & 15;
    float acc = 0.0f;
    #pragma unroll 8
    for (int n = 0; n < 128; ++n)
        acc = fmaf(qs[n * 16 + t], ks[n * 16 + s], acc);
    Gp[(size_t)(b * TGC + c) * 256 + threadIdx.x] = acc;
}

// ---------------------------------------------------------------------------
// Kernel 3: spatial flash attn + temporal softmax + yt + out-proj + residual,
// fully fused. Grid (196, 2) x 512 threads (8 waves).
// Block owns 16 s-columns x BOTH ci-halves: lane col -> n = (col>>4)*S3 +
// s0 + (col&15)  (MFMA B-cols are per-lane addresses; no contiguity needed).
// 8 waves m-split the full 6272 K/V rows round-robin (i = wave, wave+8, ...),
// partials reduced via LDS; ones-row in V gives l. Temporal A computed at
// block start from Gp (K2 output). Epilogue: ys+yt -> Ysh, then 64c x 16s
// output projection + residual. m-loop body verbatim verified round-3/6.
// ---------------------------------------------------------------------------
__global__ __launch_bounds__(512) void attn_merge_kernel(
    const ushort* __restrict__ Qb, const ushort* __restrict__ Kb,
    const ushort* __restrict__ Vb, const float* __restrict__ Gp,
    const float* __restrict__ Vt, const float* __restrict__ x,
    const float* __restrict__ Ww, const float* __restrict__ bw,
    float* __restrict__ out)
{
    __shared__ float Yred[8][17][32];    // per-wave partials: 16 y-rows + l
    __shared__ float Gpart[2][256];
    __shared__ float Lsh[256];
    __shared__ float Ash[16][17];
    __shared__ float Ysh[32][17];        // [ci][s]

    int b   = blockIdx.y;
    int s0  = blockIdx.x * 16;
    int tid = threadIdx.x;

    // --- temporal softmax (Gp ready from K2; overlaps launch ramp) ---
    {
        int j = tid & 255, g = tid >> 8;
        float a = 0.0f;
        for (int c = g; c < TGC; c += 2)
            a += Gp[(size_t)(b * TGC + c) * 256 + j];
        Gpart[g][j] = a;
    }
    __syncthreads();
    if (tid < 256) Lsh[tid] = (Gpart[0][tid] + Gpart[1][tid]) * 0.25f;
    __syncthreads();
    if (tid < 16) {
        int t = tid;
        const float* Lr = &Lsh[t * 16];
        float mx = -1e30f;
        #pragma unroll
        for (int s = 0; s < 16; ++s) mx = fmaxf(mx, Lr[s]);
        float e[16]; float sm = 0.0f;
        #pragma unroll
        for (int s = 0; s < 16; ++s) { e[s] = __expf(Lr[s] - mx); sm += e[s]; }
        float inv = 1.0f / sm;
        #pragma unroll
        for (int s = 0; s < 16; ++s) Ash[s][t] = e[s] * inv;
    }

    // --- spatial flash attention, 32x32x16, m round-robin over 8 waves ---
    int wave = __builtin_amdgcn_readfirstlane(tid >> 6);
    int lane = tid & 63;
    int col  = lane & 31;                  // n-col / m-row / t'-row lane index
    int h    = lane >> 5;                  // half: k = h*8+e
    int nq   = (col >> 4) * S3 + s0 + (col & 15);   // this lane's n column

    bf16x8 qf = *(const bf16x8*)(Qb + ((size_t)(b * NN + nq) * 16 + h * 8));

    const bf16x8 vzero = {0, 0, 0, 0, 0, 0, 0, 0};
    const bf16x8 vones = {16256, 16256, 16256, 16256, 16256, 16256, 16256, 16256};
    f32x16 yacc;
    #pragma unroll
    for (int r = 0; r < 16; ++r) yacc[r] = 0.0f;
    f32x16 zero16 = yacc;

    for (int i = wave; i < 196; i += 8) {
        int mb = i * 32;
        // K fragment (A-operand): A[row=m=mb+col][k=t=h*8+e]
        bf16x8 kf = *(const bf16x8*)(Kb + ((size_t)(b * NN + mb + col) * 16 + h * 8));
        // V fragments (A-operand) for the two PV k-steps: A[row=t'=col][k=m]
        bf16x8 vf0 = vzero, vf1 = vzero;
        if (col < 16) {
            const ushort* vp = Vb + ((size_t)(b * 16 + col) * NN + mb + h * 8);
            vf0 = *(const bf16x8*)(vp);
            vf1 = *(const bf16x8*)(vp + 16);
        } else if (col == 16) { vf0 = vones; vf1 = vones; }   // l-row

        // S^T tile: D[m-row][n-col], rows (r&3)+8*(r>>2)+4h, col = n
        f32x16 st = __builtin_amdgcn_mfma_f32_32x32x16_bf16(kf, qf, zero16, 0, 0, 0);
        float pv[16];
        #pragma unroll
        for (int r = 0; r < 16; ++r) pv[r] = __builtin_amdgcn_exp2f(st[r]);

        // pack to bf16 pairs; permlane32_swap routes rows to B-operand k-slots
        uint X0 = cvtpk(pv[0],  pv[1]),  X1 = cvtpk(pv[2],  pv[3]);
        uint Y0 = cvtpk(pv[4],  pv[5]),  Y1 = cvtpk(pv[6],  pv[7]);
        uint X2 = cvtpk(pv[8],  pv[9]),  X3 = cvtpk(pv[10], pv[11]);
        uint Y2 = cvtpk(pv[12], pv[13]), Y3 = cvtpk(pv[14], pv[15]);
        swap32(X0, Y0); swap32(X1, Y1);
        swap32(X2, Y2); swap32(X3, Y3);
        u32x4 pb0 = {X0, X1, Y0, Y1};    // B-frag rows mb+0..15
        u32x4 pb1 = {X2, X3, Y2, Y3};    // B-frag rows mb+16..31

        yacc = __builtin_amdgcn_mfma_f32_32x32x16_bf16(
                   vf0, __builtin_bit_cast(bf16x8, pb0), yacc, 0, 0, 0);
        yacc = __builtin_amdgcn_mfma_f32_32x32x16_bf16(
                   vf1, __builtin_bit_cast(bf16x8, pb1), yacc, 0, 0, 0);
    }

    // per-wave partials to LDS: rows 0..15 = y[t], row 16 = l (h==0 reg 8)
    #pragma unroll
    for (int r = 0; r < 8; ++r) {
        int t = (r & 3) + 8 * (r >> 2) + 4 * h;
        Yred[wave][t][col] = yacc[r];
    }
    if (h == 0) Yred[wave][16][col] = yacc[8];
    __syncthreads();

    // --- epilogue 1: one (t, col) per thread -> Ysh[ci][s] = ys + yt ---
    {
        int t    = tid >> 5;               // 0..15
        int c2   = tid & 31;
        float ysum = 0.0f, lsum = 0.0f;
        #pragma unroll
        for (int w = 0; w < 8; ++w) {
            ysum += Yred[w][t][c2];
            lsum += Yred[w][16][c2];
        }
        float ys = ysum / lsum;

        int t2   = c2 & 15;                // s within chunk
        int half = c2 >> 4;
        const float4* vp = (const float4*)(Vt + (size_t)b * PB + (size_t)t * NN
                                           + (size_t)half * S3 + s0);
        float4 v0 = vp[0], v1 = vp[1], v2 = vp[2], v3 = vp[3];
        float yt = Ash[0][t2] * v0.x;
        yt = fmaf(Ash[1][t2],  v0.y, yt); yt = fmaf(Ash[2][t2],  v0.z, yt);
        yt = fmaf(Ash[3][t2],  v0.w, yt); yt = fmaf(Ash[4][t2],  v1.x, yt);
        yt = fmaf(Ash[5][t2],  v1.y, yt); yt = fmaf(Ash[6][t2],  v1.z, yt);
        yt = fmaf(Ash[7][t2],  v1.w, yt); yt = fmaf(Ash[8][t2],  v2.x, yt);
        yt = fmaf(Ash[9][t2],  v2.y, yt); yt = fmaf(Ash[10][t2], v2.z, yt);
        yt = fmaf(Ash[11][t2], v2.w, yt); yt = fmaf(Ash[12][t2], v3.x, yt);
        yt = fmaf(Ash[13][t2], v3.y, yt); yt = fmaf(Ash[14][t2], v3.z, yt);
        yt = fmaf(Ash[15][t2], v3.w, yt);

        Ysh[2 * t + half][t2] = ys + yt;   // [ci][s]
    }
    __syncthreads();

    // --- epilogue 2: output projection + residual, 64c x 16s, 2 per thread ---
    {
        int s  = tid & 15;
        int cg = tid >> 4;                 // 0..31
        #pragma unroll
        for (int kk = 0; kk < 2; ++kk) {
            int c = cg + kk * 32;
            float acc = bw[c];
            const float4* wr = (const float4*)(Ww + c * 32);
            #pragma unroll
            for (int cb = 0; cb < 8; ++cb) {
                float4 w4 = wr[cb];
                acc = fmaf(w4.x, Ysh[cb * 4 + 0][s], acc);
                acc = fmaf(w4.y, Ysh[cb * 4 + 1][s], acc);
                acc = fmaf(w4.z, Ysh[cb * 4 + 2][s], acc);
                acc = fmaf(w4.w, Ysh[cb * 4 + 3][s], acc);
            }
            size_t o = (size_t)b * XB + (size_t)c * S3 + s0 + s;
            out[o] = x[o] + acc;
        }
    }
}

// ---------------------------------------------------------------------------
extern "C" void kernel_launch(void* const* d_in, const int* in_sizes, int n_in,
                              void* d_out, int out_size, void* d_ws, size_t ws_size,
                              hipStream_t stream)
{
    const float* x   = (const float*)d_in[0];
    const float* Wqs = (const float*)d_in[1];  const float* bqs = (const float*)d_in[2];
    const float* Wks = (const float*)d_in[3];  const float* bks = (const float*)d_in[4];
    const float* Wvs = (const float*)d_in[5];  const float* bvs = (const float*)d_in[6];
    const float* Wqt = (const float*)d_in[7];  const float* bqt = (const float*)d_in[8];
    const float* Wkt = (const float*)d_in[9];  const float* bkt = (const float*)d_in[10];
    const float* Wvt = (const float*)d_in[11]; const float* bvt = (const float*)d_in[12];
    const float* Ww  = (const float*)d_in[13]; const float* bw  = (const float*)d_in[14];

    // workspace layout (float units); ~0.93M floats = 3.7 MB
    float* ws = (float*)d_ws;
    ushort* Qb = (ushort*)(ws);            // 200704 bf16
    ushort* Kb = (ushort*)(ws + 100352);
    ushort* Vb = (ushort*)(ws + 200704);
    float* Qt  = ws + 301056;              // 200704
    float* Kt  = ws + 501760;
    float* Vt  = ws + 702464;
    float* Gp  = ws + 903168;              // 2*49*256 = 25088

    proj_kernel<<<dim3(25, 6, 8), 256, 0, stream>>>(
        x, Wqs, bqs, Wks, bks, Wvs, bvs, Wqt, bqt, Wkt, bkt, Wvt, bvt,
        Qb, Kb, Vb, Qt, Kt, Vt);

    gram_kernel<<<dim3(TGC, 2), 256, 0, stream>>>(Qt, Kt, Gp);

    attn_merge_kernel<<<dim3(196, 2), 512, 0, stream>>>(
        Qb, Kb, Vb, Gp, Vt, x, Ww, bw, (float*)d_out);
}